// Round 1
// baseline (26.255 us; speedup 1.0000x reference)
//
#include <hip/hip_runtime.h>

// MahalanobisClassifier: out[b,c] = -sum_d (x[b,d]-p[c,d])^2 * exp(ld[c,d])
// Decomposition: out = -( A'.B' + s[c] ), one bf16 MFMA GEMM with K=512:
//   A'[b,k]  = k<256 ? x[b,k]^2        : x[b,k-256]
//   B'[c,k]  = k<256 ? w[c,k]          : -2*p[c,k-256]*w[c,k-256]   (w = exp(ld))
//   s[c]     = sum_d p^2 * w
// B=2048, C=1000 (padded to 1024 with zero rows), D=256, K=512.
//
// ws layout: A_ws bf16 [2 MB] | B_ws bf16 [1 MB] | s_ws f32 [4 KB]
// A_ws/B_ws are stored in MFMA-fragment order [tile16][ktile32][lane64][8 bf16]
// so the GEMM can stage with linear global_load_lds (16B) and read fragments
// with lane-linear (conflict-free) ds_read_b128.

#define B_N 2048
#define C_N 1000
#define D_N 256
#define K_N 512

typedef __attribute__((ext_vector_type(8))) short bf16x8;
typedef __attribute__((ext_vector_type(8))) unsigned short u16x8;
typedef __attribute__((ext_vector_type(4))) float f32x4;

__device__ inline unsigned short f2bf(float f) {
  // round-to-nearest-even fp32 -> bf16 (finite inputs)
  unsigned int u = __float_as_uint(f);
  unsigned int lsb = (u >> 16) & 1u;
  u += 0x7fffu + lsb;
  return (unsigned short)(u >> 16);
}

__device__ inline void gload16(const void* g, void* l) {
  __builtin_amdgcn_global_load_lds(
      (const __attribute__((address_space(1))) unsigned int*)g,
      (__attribute__((address_space(3))) unsigned int*)l, 16, 0, 0);
}

// ---------- prep A': one thread per 8-elem chunk; 2048/16 * 16 * 64 = 131072 chunks
__global__ void prep_a(const float* __restrict__ x, unsigned short* __restrict__ aws) {
  int cid = blockIdx.x * 256 + threadIdx.x;   // == (i*16 + t)*64 + l
  int l = cid & 63;
  int t = (cid >> 6) & 15;
  int i = cid >> 10;                          // m16 tile 0..127
  int b = i * 16 + (l & 15);
  int k = t * 32 + ((l >> 4) * 8);
  bool sq = (k < D_N);
  int kk = sq ? k : k - D_N;
  const float* src = x + (size_t)b * D_N + kk;
  float4 v0 = *reinterpret_cast<const float4*>(src);
  float4 v1 = *reinterpret_cast<const float4*>(src + 4);
  float v[8] = {v0.x, v0.y, v0.z, v0.w, v1.x, v1.y, v1.z, v1.w};
  u16x8 o;
#pragma unroll
  for (int j = 0; j < 8; ++j) {
    float f = sq ? v[j] * v[j] : v[j];
    o[j] = f2bf(f);
  }
  *reinterpret_cast<u16x8*>(aws + (size_t)cid * 8) = o;
}

// ---------- prep B': 1024/16 * 16 * 64 = 65536 chunks (zero rows for c>=1000)
__global__ void prep_b(const float* __restrict__ p, const float* __restrict__ ld,
                       unsigned short* __restrict__ bws) {
  int cid = blockIdx.x * 256 + threadIdx.x;
  int l = cid & 63;
  int t = (cid >> 6) & 15;
  int j = cid >> 10;                          // n16 tile 0..63
  int c = j * 16 + (l & 15);
  int k = t * 32 + ((l >> 4) * 8);
  u16x8 o;
#pragma unroll
  for (int jj = 0; jj < 8; ++jj) o[jj] = 0;
  if (c < C_N) {
    bool first = (k < D_N);
    int kk = first ? k : k - D_N;
    const float* lp = ld + (size_t)c * D_N + kk;
    const float* pp = p + (size_t)c * D_N + kk;
#pragma unroll
    for (int jj = 0; jj < 8; ++jj) {
      float w = __expf(lp[jj]);
      float val = first ? w : (-2.0f * pp[jj] * w);
      o[jj] = f2bf(val);
    }
  }
  *reinterpret_cast<u16x8*>(bws + (size_t)cid * 8) = o;
}

// ---------- prep s[c] = sum_d p^2 * exp(ld); one wave per c, 4 c per block
__global__ void prep_s(const float* __restrict__ p, const float* __restrict__ ld,
                       float* __restrict__ sws) {
  int c = blockIdx.x * 4 + (threadIdx.x >> 6);  // 0..999 exactly (250 blocks)
  int l = threadIdx.x & 63;
  float sum = 0.f;
#pragma unroll
  for (int q = 0; q < 4; ++q) {
    int k = q * 64 + l;
    float pv = p[(size_t)c * D_N + k];
    float w = __expf(ld[(size_t)c * D_N + k]);
    sum += pv * pv * w;
  }
#pragma unroll
  for (int off = 32; off > 0; off >>= 1) sum += __shfl_down(sum, off, 64);
  if (l == 0) sws[c] = sum;
}

// ---------- GEMM: 128x64 block tile, 4 waves (2x2), wave tile 64x32, K=512 (16 steps)
__global__ __launch_bounds__(256) void gemm_kernel(
    const unsigned short* __restrict__ aws, const unsigned short* __restrict__ bws,
    const float* __restrict__ sws, float* __restrict__ out) {
  // per K-step buffer: A 8 tiles * 1KB = 8192B, B 4 tiles * 1KB = 4096B
  __shared__ char smem[2 * 12288];
  const int tid = threadIdx.x;
  const int bm = blockIdx.x;   // 0..15  (rows of 128)
  const int bn = blockIdx.y;   // 0..15  (cols of 64)
  const int w = tid >> 6, l = tid & 63;
  const int wm = w >> 1, wn = w & 1;

  const char* ga = (const char*)aws;
  const char* gb = (const char*)bws;
  const int lane16 = (tid & 63) * 16;
  // global byte offsets, excluding the +t*1024 k-tile term
  const size_t a_g0 = (size_t)((bm * 8 + (tid >> 6)) * 16) * 1024 + lane16;
  const size_t a_g1 = (size_t)((bm * 8 + 4 + (tid >> 6)) * 16) * 1024 + lane16;
  const size_t b_g0 = (size_t)((bn * 4 + (tid >> 6)) * 16) * 1024 + lane16;

  f32x4 acc[4][2];
#pragma unroll
  for (int i = 0; i < 4; ++i)
#pragma unroll
    for (int jn = 0; jn < 2; ++jn) acc[i][jn] = {0.f, 0.f, 0.f, 0.f};

  auto stage = [&](int t, char* buf) {
    gload16(ga + a_g0 + (size_t)t * 1024, buf + tid * 16);
    gload16(ga + a_g1 + (size_t)t * 1024, buf + 4096 + tid * 16);
    gload16(gb + b_g0 + (size_t)t * 1024, buf + 8192 + tid * 16);
  };

  stage(0, smem);
  __syncthreads();                       // drains vmcnt before first compute

#pragma unroll 1
  for (int t = 0; t < 16; ++t) {
    char* buf = smem + (t & 1) * 12288;
    if (t < 15) stage(t + 1, smem + ((t + 1) & 1) * 12288);
    bf16x8 af[4], bfg[2];
#pragma unroll
    for (int i = 0; i < 4; ++i)
      af[i] = *reinterpret_cast<const bf16x8*>(buf + ((wm * 4 + i) * 64 + l) * 16);
#pragma unroll
    for (int jn = 0; jn < 2; ++jn)
      bfg[jn] = *reinterpret_cast<const bf16x8*>(buf + 8192 + ((wn * 2 + jn) * 64 + l) * 16);
#pragma unroll
    for (int i = 0; i < 4; ++i)
#pragma unroll
      for (int jn = 0; jn < 2; ++jn)
        acc[i][jn] = __builtin_amdgcn_mfma_f32_16x16x32_bf16(af[i], bfg[jn], acc[i][jn], 0, 0, 0);
    __syncthreads();                     // stage(t+1) visible; buf free for t+2
  }

  // epilogue: C/D layout col=lane&15, row=(lane>>4)*4+reg  [guide §3, m89/m91]
  const int colbase = bn * 64 + wn * 32 + (l & 15);
  const int rowbase = bm * 128 + wm * 64 + (l >> 4) * 4;
#pragma unroll
  for (int jn = 0; jn < 2; ++jn) {
    int col = colbase + jn * 16;
    if (col < C_N) {
      float sc = sws[col];
#pragma unroll
      for (int i = 0; i < 4; ++i) {
        int row = rowbase + i * 16;
#pragma unroll
        for (int r = 0; r < 4; ++r)
          out[(size_t)(row + r) * C_N + col] = -(acc[i][jn][r] + sc);
      }
    }
  }
}

extern "C" void kernel_launch(void* const* d_in, const int* in_sizes, int n_in,
                              void* d_out, int out_size, void* d_ws, size_t ws_size,
                              hipStream_t stream) {
  const float* x  = (const float*)d_in[0];
  const float* p  = (const float*)d_in[1];
  const float* ld = (const float*)d_in[2];
  float* out = (float*)d_out;

  unsigned short* aws = (unsigned short*)d_ws;                          // 2 MB
  unsigned short* bws = (unsigned short*)((char*)d_ws + 2u * 1024 * 1024); // 1 MB
  float* sws = (float*)((char*)d_ws + 3u * 1024 * 1024);                // 4 KB

  prep_a<<<512, 256, 0, stream>>>(x, aws);
  prep_b<<<256, 256, 0, stream>>>(p, ld, bws);
  prep_s<<<250, 256, 0, stream>>>(p, ld, sws);
  gemm_kernel<<<dim3(16, 16), 256, 0, stream>>>(aws, bws, sws, out);
}

// Round 2
// 17.451 us; speedup vs baseline: 1.5045x; 1.5045x over previous
//
#include <hip/hip_runtime.h>

// MahalanobisClassifier, fully fused single dispatch.
// out[b,c] = -sum_d (x-p)^2 * exp(ld) = -( sum_d x^2*w - 2 sum_d x*(p*w) + s[c] )
// One bf16 MFMA GEMM, K=512 concat: A'=[x^2 | x] (2048x512), B'=[w | -2*p*w] (1024x512),
// s[c] = sum_d p^2*w added in epilogue. Each block preps its tiles in LDS directly
// from f32 inputs (no workspace, no extra dispatches).
//
// Block = 256 threads (4 waves, 2x2), grid (16,16):
//   blockIdx.x -> 128 rows (two 64-row m-tiles sharing one B'-tile prep)
//   blockIdx.y -> 64 classes
// LDS fragment order [tile16][ktile][lane][8 bf16] => all ds accesses lane-linear.

#define C_N 1000
#define D_N 256

typedef __attribute__((ext_vector_type(8))) short bf16x8;
typedef __attribute__((ext_vector_type(4))) float f32x4;

__device__ inline short f2bf(float f) {
  unsigned int u = __float_as_uint(f);
  unsigned int lsb = (u >> 16) & 1u;
  u += 0x7fffu + lsb;
  return (short)(u >> 16);
}

__global__ __launch_bounds__(256) void mahal_fused(
    const float* __restrict__ x, const float* __restrict__ p,
    const float* __restrict__ ld, float* __restrict__ out) {
  // A': 4 i-tiles x 16 ktiles x 64 lanes x 8 bf16 = 64 KB ; B' same ; s 256 B
  __shared__ short lA[4][16][64][8];
  __shared__ short lB[4][16][64][8];
  __shared__ float s_lds[64];

  const int tid = threadIdx.x;
  const int w   = tid >> 6;        // wave 0..3
  const int l   = tid & 63;
  const int r16 = l & 15;
  const int hi  = l >> 4;
  const int bx  = blockIdx.x;      // 0..15 : rows bx*128 .. +127
  const int by  = blockIdx.y;      // 0..15 : cols by*64 .. +63

  // ---------- prep B' (each wave owns j-tile w) + fused s[c] ----------
  {
    const int c = by * 64 + w * 16 + r16;
    const bool valid = (c < C_N);
    float sp = 0.f;
#pragma unroll
    for (int t = 0; t < 8; ++t) {
      const int d = t * 32 + hi * 8;
      short wv[8], pw[8];
      if (valid) {
        const float* lp = ld + (size_t)c * D_N + d;
        const float* pp = p  + (size_t)c * D_N + d;
        float4 l0 = *reinterpret_cast<const float4*>(lp);
        float4 l1 = *reinterpret_cast<const float4*>(lp + 4);
        float4 p0 = *reinterpret_cast<const float4*>(pp);
        float4 p1 = *reinterpret_cast<const float4*>(pp + 4);
        float lv[8] = {l0.x, l0.y, l0.z, l0.w, l1.x, l1.y, l1.z, l1.w};
        float pv[8] = {p0.x, p0.y, p0.z, p0.w, p1.x, p1.y, p1.z, p1.w};
#pragma unroll
        for (int j = 0; j < 8; ++j) {
          float wj = __expf(lv[j]);
          wv[j] = f2bf(wj);
          pw[j] = f2bf(-2.f * pv[j] * wj);
          sp += pv[j] * pv[j] * wj;
        }
      } else {
#pragma unroll
        for (int j = 0; j < 8; ++j) { wv[j] = 0; pw[j] = 0; }
      }
      *reinterpret_cast<bf16x8*>(&lB[w][t][l][0])     = *reinterpret_cast<bf16x8*>(wv);
      *reinterpret_cast<bf16x8*>(&lB[w][t + 8][l][0]) = *reinterpret_cast<bf16x8*>(pw);
    }
    // s[c]: 4 partials live at lanes hi*16 + r16 of this wave
    sp += __shfl_xor(sp, 16, 64);
    sp += __shfl_xor(sp, 32, 64);
    if (l < 16) s_lds[w * 16 + r16] = sp;
  }

  // ---------- prep A' for one 64-row m-tile (wave owns i-tile w) ----------
  auto prepA = [&](int mt) {
    const int row = bx * 128 + mt * 64 + w * 16 + r16;
#pragma unroll
    for (int t = 0; t < 8; ++t) {
      const int d = t * 32 + hi * 8;
      const float* xp = x + (size_t)row * D_N + d;
      float4 v0 = *reinterpret_cast<const float4*>(xp);
      float4 v1 = *reinterpret_cast<const float4*>(xp + 4);
      float v[8] = {v0.x, v0.y, v0.z, v0.w, v1.x, v1.y, v1.z, v1.w};
      short sq[8], rw[8];
#pragma unroll
      for (int j = 0; j < 8; ++j) {
        sq[j] = f2bf(v[j] * v[j]);
        rw[j] = f2bf(v[j]);
      }
      *reinterpret_cast<bf16x8*>(&lA[w][t][l][0])     = *reinterpret_cast<bf16x8*>(sq);
      *reinterpret_cast<bf16x8*>(&lA[w][t + 8][l][0]) = *reinterpret_cast<bf16x8*>(rw);
    }
  };

  // ---------- compute 64x64 (wave tile 32x32, 2x2) + epilogue ----------
  const int wm = w >> 1, wn = w & 1;
  auto computeStore = [&](int mt) {
    f32x4 acc[2][2];
#pragma unroll
    for (int i = 0; i < 2; ++i)
#pragma unroll
      for (int jn = 0; jn < 2; ++jn) acc[i][jn] = {0.f, 0.f, 0.f, 0.f};
#pragma unroll
    for (int kt = 0; kt < 16; ++kt) {
      bf16x8 a0 = *reinterpret_cast<const bf16x8*>(&lA[wm * 2 + 0][kt][l][0]);
      bf16x8 a1 = *reinterpret_cast<const bf16x8*>(&lA[wm * 2 + 1][kt][l][0]);
      bf16x8 b0 = *reinterpret_cast<const bf16x8*>(&lB[wn * 2 + 0][kt][l][0]);
      bf16x8 b1 = *reinterpret_cast<const bf16x8*>(&lB[wn * 2 + 1][kt][l][0]);
      acc[0][0] = __builtin_amdgcn_mfma_f32_16x16x32_bf16(a0, b0, acc[0][0], 0, 0, 0);
      acc[0][1] = __builtin_amdgcn_mfma_f32_16x16x32_bf16(a0, b1, acc[0][1], 0, 0, 0);
      acc[1][0] = __builtin_amdgcn_mfma_f32_16x16x32_bf16(a1, b0, acc[1][0], 0, 0, 0);
      acc[1][1] = __builtin_amdgcn_mfma_f32_16x16x32_bf16(a1, b1, acc[1][1], 0, 0, 0);
    }
    // C/D layout: col = lane&15, row = (lane>>4)*4 + reg   [verified in round-1 kernel]
    const int colbase = by * 64 + wn * 32 + r16;
    const int rowbase = bx * 128 + mt * 64 + wm * 32 + hi * 4;
#pragma unroll
    for (int jn = 0; jn < 2; ++jn) {
      const int col = colbase + jn * 16;
      if (col < C_N) {
        const float sc = s_lds[wn * 32 + jn * 16 + r16];
#pragma unroll
        for (int i = 0; i < 2; ++i) {
          const int row = rowbase + i * 16;
#pragma unroll
          for (int r = 0; r < 4; ++r)
            out[(size_t)(row + r) * C_N + col] = -(acc[i][jn][r] + sc);
        }
      }
    }
  };

  prepA(0);
  __syncthreads();          // B', A'(0), s visible to all waves
  computeStore(0);
  __syncthreads();          // everyone done reading A'(0)
  prepA(1);
  __syncthreads();          // A'(1) visible
  computeStore(1);
}

extern "C" void kernel_launch(void* const* d_in, const int* in_sizes, int n_in,
                              void* d_out, int out_size, void* d_ws, size_t ws_size,
                              hipStream_t stream) {
  const float* x  = (const float*)d_in[0];
  const float* p  = (const float*)d_in[1];
  const float* ld = (const float*)d_in[2];
  float* out = (float*)d_out;
  mahal_fused<<<dim3(16, 16), 256, 0, stream>>>(x, p, ld, out);
}